// Round 8
// baseline (183.408 us; speedup 1.0000x reference)
//
#include <hip/hip_runtime.h>

#define NN 8
#define MM 8
#define NH1 64
#define NH2 32

#define FOR8(OP) OP(0) OP(1) OP(2) OP(3) OP(4) OP(5) OP(6) OP(7)

typedef float v2f __attribute__((ext_vector_type(2)));

struct U8 { float u0, u1, u2, u3, u4, u5, u6, u7; };

// ---- QP helper macros (expand inside qp_solve over named scalars) ----
#define CTERM(j) { float u = fmaf(lam, g##j, -p##j);                   \
                   u = fminf(fmaxf(u, -1.0f), 1.0f);                   \
                   c = fmaf(g##j, u, c); }
#define BP(j) {                                                        \
        const float rg = __builtin_amdgcn_rcpf(g##j);                  \
        const float bpa = (p##j - 1.0f) * rg;                          \
        const float bpb = (p##j + 1.0f) * rg;                          \
        const float ca = c_of(bpa);                                    \
        const float cb = c_of(bpb);                                    \
        lamL = (bpa > 0.0f && ca <  0.0f && bpa > lamL) ? bpa : lamL;  \
        lamR = (bpa > 0.0f && ca >= 0.0f && bpa < lamR) ? bpa : lamR;  \
        lamL = (bpb > 0.0f && cb <  0.0f && bpb > lamL) ? bpb : lamL;  \
        lamR = (bpb > 0.0f && cb >= 0.0f && bpb < lamR) ? bpb : lamR;  \
    }
#define ASET(j)                                                        \
    const float ur##j = fmaf(lam_t, g##j, -p##j);                      \
    const bool lo##j = (ur##j <= -1.0f);                               \
    const bool hi##j = (ur##j >=  1.0f);                               \
    denom += (!(lo##j || hi##j)) ? g##j * g##j : 0.0f;                 \
    num   += lo##j ? -g##j : (hi##j ? g##j : -g##j * p##j);
#define UOUT(j) const float uo##j =                                    \
    lo##j ? -1.0f : (hi##j ? 1.0f : fmaf(lam, g##j, -p##j));

// Exact piecewise-linear root isolation + frozen-active-set KKT refinement.
// All-scalar params/locals -> pure registers (round-3 lesson).
__device__ __forceinline__ U8 qp_solve(
    float c0,
    float p0, float p1, float p2, float p3,
    float p4, float p5, float p6, float p7,
    float g0, float g1, float g2, float g3,
    float g4, float g5, float g6, float g7)
{
    auto c_of = [&](float lam) -> float {
        float c = c0;
        FOR8(CTERM)
        return c;
    };

    const bool viol = (c_of(0.0f) < 0.0f);

    const float BIGR = 3.0e38f;          // sentinel: no right bracket found
    float lamL = 0.0f, lamR = BIGR;
    FOR8(BP)

    // lam_t strictly inside the root's segment (same segment the reference's
    // bisection lands in). Infeasible => classify at the capped bracket 2^40.
    const bool infeas = (lamR == BIGR);
    float lam_t = infeas ? 1.099511627776e12f : 0.5f * (lamL + lamR);
    lam_t = viol ? lam_t : 0.0f;

    float denom = 0.0f, num = c0;
    FOR8(ASET)

    const float lam = viol ? (-num / (denom + 1e-12f)) : 0.0f;
    FOR8(UOUT)

    return U8{uo0, uo1, uo2, uo3, uo4, uo5, uo6, uo7};
}

__global__ __launch_bounds__(256, 2) void barrier_policy_kernel(
    const float* __restrict__ x_g,
    const float* __restrict__ W1,  const float* __restrict__ b1,
    const float* __restrict__ W21, const float* __restrict__ b21,
    const float* __restrict__ W22, const float* __restrict__ b22,
    const float* __restrict__ W31, const float* __restrict__ b31,
    const float* __restrict__ W32, const float* __restrict__ b32,
    const float* __restrict__ Amat, const float* __restrict__ Gmat,
    const float* __restrict__ mean, const float* __restrict__ std_,
    float* __restrict__ out, int B)
{
    const int tid = threadIdx.x;
    const int rA = blockIdx.x * 512 + tid;     // row A
    if (rA >= B) return;
    const int rB = rA + 256;                    // row B (same wave, +256)
    const bool vB = (rB < B);
    const int rBl = vB ? rB : rA;               // clamped for safe loads

    // ---- load x for both rows (vectorized) ----
    float xA[NN], xB[NN];
    {
        const float4* xva = reinterpret_cast<const float4*>(x_g + (size_t)rA * NN);
        const float4* xvb = reinterpret_cast<const float4*>(x_g + (size_t)rBl * NN);
        float4 a0 = xva[0], a1 = xva[1], b0 = xvb[0], b1v_ = xvb[1];
        xA[0]=a0.x; xA[1]=a0.y; xA[2]=a0.z; xA[3]=a0.w;
        xA[4]=a1.x; xA[5]=a1.y; xA[6]=a1.z; xA[7]=a1.w;
        xB[0]=b0.x; xB[1]=b0.y; xB[2]=b0.z; xB[3]=b0.w;
        xB[4]=b1v_.x; xB[5]=b1v_.y; xB[6]=b1v_.z; xB[7]=b1v_.w;
    }

    // ---- un-normalized state (shared mean/std loads) ----
    float x0A[NN], x0B[NN];
#pragma unroll
    for (int i = 0; i < NN; ++i) {
        const float sd = std_[i], mn = mean[i];
        x0A[i] = fmaf(xA[i], sd, mn);
        x0B[i] = fmaf(xB[i], sd, mn);
    }

    // =====================================================================
    // MLP, packed FP32, 2 rows/thread. Weight loads shared across rows;
    // per-row accumulation order bitwise-identical to the round-6 kernel.
    // =====================================================================
    v2f a21A[NH2/2], a22A[NH2/2], a21B[NH2/2], a22B[NH2/2];
#pragma unroll
    for (int j2 = 0; j2 < NH2/2; ++j2) {
        const v2f i21 = *(const v2f*)(b21 + 2*j2);
        const v2f i22 = *(const v2f*)(b22 + 2*j2);
        a21A[j2] = i21; a21B[j2] = i21;
        a22A[j2] = i22; a22B[j2] = i22;
    }

#pragma unroll
    for (int k2 = 0; k2 < NH1/2; ++k2) {
        // ---- layer-1 pair h[2k2], h[2k2+1] for both rows ----
        const v2f bini = *(const v2f*)(b1 + 2*k2);
        v2f accA = bini, accB = bini;
#pragma unroll
        for (int i = 0; i < NN; ++i) {
            const v2f w = *(const v2f*)(W1 + i * NH1 + 2*k2);
            const v2f xia = { xA[i], xA[i] };
            const v2f xib = { xB[i], xB[i] };
            accA = __builtin_elementwise_fma(xia, w, accA);
            accB = __builtin_elementwise_fma(xib, w, accB);
        }
        const v2f zero2 = { 0.0f, 0.0f };
        const v2f h2A = __builtin_elementwise_max(accA, zero2);
        const v2f h2B = __builtin_elementwise_max(accB, zero2);

        const v2f haA = h2A.xx, hbA = h2A.yy;
        const v2f haB = h2B.xx, hbB = h2B.yy;

        const float4* w21a4 = (const float4*)(W21 + (2*k2)     * NH2);
        const float4* w21b4 = (const float4*)(W21 + (2*k2 + 1) * NH2);
        const float4* w22a4 = (const float4*)(W22 + (2*k2)     * NH2);
        const float4* w22b4 = (const float4*)(W22 + (2*k2 + 1) * NH2);

        // phase a: h[2k2] into both heads, both rows (float4 weight loads)
#pragma unroll
        for (int j4 = 0; j4 < NH2/4; ++j4) {
            const float4 wa21 = w21a4[j4];
            const float4 wa22 = w22a4[j4];
            const v2f w21lo = { wa21.x, wa21.y }, w21hi = { wa21.z, wa21.w };
            const v2f w22lo = { wa22.x, wa22.y }, w22hi = { wa22.z, wa22.w };
            a21A[2*j4]   = __builtin_elementwise_fma(haA, w21lo, a21A[2*j4]);
            a21B[2*j4]   = __builtin_elementwise_fma(haB, w21lo, a21B[2*j4]);
            a21A[2*j4+1] = __builtin_elementwise_fma(haA, w21hi, a21A[2*j4+1]);
            a21B[2*j4+1] = __builtin_elementwise_fma(haB, w21hi, a21B[2*j4+1]);
            a22A[2*j4]   = __builtin_elementwise_fma(haA, w22lo, a22A[2*j4]);
            a22B[2*j4]   = __builtin_elementwise_fma(haB, w22lo, a22B[2*j4]);
            a22A[2*j4+1] = __builtin_elementwise_fma(haA, w22hi, a22A[2*j4+1]);
            a22B[2*j4+1] = __builtin_elementwise_fma(haB, w22hi, a22B[2*j4+1]);
        }
        // phase b: h[2k2+1]
#pragma unroll
        for (int j4 = 0; j4 < NH2/4; ++j4) {
            const float4 wb21 = w21b4[j4];
            const float4 wb22 = w22b4[j4];
            const v2f w21lo = { wb21.x, wb21.y }, w21hi = { wb21.z, wb21.w };
            const v2f w22lo = { wb22.x, wb22.y }, w22hi = { wb22.z, wb22.w };
            a21A[2*j4]   = __builtin_elementwise_fma(hbA, w21lo, a21A[2*j4]);
            a21B[2*j4]   = __builtin_elementwise_fma(hbB, w21lo, a21B[2*j4]);
            a21A[2*j4+1] = __builtin_elementwise_fma(hbA, w21hi, a21A[2*j4+1]);
            a21B[2*j4+1] = __builtin_elementwise_fma(hbB, w21hi, a21B[2*j4+1]);
            a22A[2*j4]   = __builtin_elementwise_fma(hbA, w22lo, a22A[2*j4]);
            a22B[2*j4]   = __builtin_elementwise_fma(hbB, w22lo, a22B[2*j4]);
            a22A[2*j4+1] = __builtin_elementwise_fma(hbA, w22hi, a22A[2*j4+1]);
            a22B[2*j4+1] = __builtin_elementwise_fma(hbB, w22hi, a22B[2*j4+1]);
        }
    }
    {
        const v2f zero2 = { 0.0f, 0.0f };
#pragma unroll
        for (int j2 = 0; j2 < NH2/2; ++j2) {
            a21A[j2] = __builtin_elementwise_max(a21A[j2], zero2);
            a21B[j2] = __builtin_elementwise_max(a21B[j2], zero2);
            a22A[j2] = __builtin_elementwise_max(a22A[j2], zero2);
            a22B[j2] = __builtin_elementwise_max(a22B[j2], zero2);
        }
    }

    // ---- p-head (float4 weight loads, shared across rows) ----
    v2f pvA[MM/2], pvB[MM/2];
#pragma unroll
    for (int j2 = 0; j2 < MM/2; ++j2) {
        const v2f ib = *(const v2f*)(b31 + 2*j2);
        pvA[j2] = ib; pvB[j2] = ib;
    }
#pragma unroll
    for (int k2 = 0; k2 < NH2/2; ++k2) {
        const v2f hkaA = a21A[k2].xx, hkbA = a21A[k2].yy;
        const v2f hkaB = a21B[k2].xx, hkbB = a21B[k2].yy;
        const float4* w31a4 = (const float4*)(W31 + (2*k2)     * MM);
        const float4* w31b4 = (const float4*)(W31 + (2*k2 + 1) * MM);
#pragma unroll
        for (int j4 = 0; j4 < MM/4; ++j4) {
            const float4 wa = w31a4[j4];
            const v2f wlo = { wa.x, wa.y }, whi = { wa.z, wa.w };
            pvA[2*j4]   = __builtin_elementwise_fma(hkaA, wlo, pvA[2*j4]);
            pvB[2*j4]   = __builtin_elementwise_fma(hkaB, wlo, pvB[2*j4]);
            pvA[2*j4+1] = __builtin_elementwise_fma(hkaA, whi, pvA[2*j4+1]);
            pvB[2*j4+1] = __builtin_elementwise_fma(hkaB, whi, pvB[2*j4+1]);
        }
#pragma unroll
        for (int j4 = 0; j4 < MM/4; ++j4) {
            const float4 wb = w31b4[j4];
            const v2f wlo = { wb.x, wb.y }, whi = { wb.z, wb.w };
            pvA[2*j4]   = __builtin_elementwise_fma(hkbA, wlo, pvA[2*j4]);
            pvB[2*j4]   = __builtin_elementwise_fma(hkbB, wlo, pvB[2*j4]);
            pvA[2*j4+1] = __builtin_elementwise_fma(hkbA, whi, pvA[2*j4+1]);
            pvB[2*j4+1] = __builtin_elementwise_fma(hkbB, whi, pvB[2*j4+1]);
        }
    }

    // ---- alpha-head: scalar, shared W32 loads ----
    float sA = b32[0];
    float sB = sA;
#pragma unroll
    for (int k2 = 0; k2 < NH2/2; ++k2) {
        const float wa = W32[2*k2], wb = W32[2*k2 + 1];
        sA = fmaf(a22A[k2].x, wa, sA); sA = fmaf(a22A[k2].y, wb, sA);
        sB = fmaf(a22B[k2].x, wa, sB); sB = fmaf(a22B[k2].y, wb, sB);
    }
    const float alphaA = 4.0f / (1.0f + __expf(-sA));
    const float alphaB = 4.0f / (1.0f + __expf(-sB));

    // ---- barrier terms (shared A/G loads) ----
    float hxA = 16.0f, hxB = 16.0f;
#pragma unroll
    for (int i = 0; i < NN; ++i) {
        hxA = fmaf(-x0A[i], x0A[i], hxA);
        hxB = fmaf(-x0B[i], x0B[i], hxB);
    }
    float dhA[NN], dhB[NN];
#pragma unroll
    for (int i = 0; i < NN; ++i) { dhA[i] = -2.0f * x0A[i]; dhB[i] = -2.0f * x0B[i]; }

    float LfA = 0.0f, LfB = 0.0f;
#pragma unroll
    for (int i = 0; i < NN; ++i) {
        float fxA = 0.0f, fxB = 0.0f;
#pragma unroll
        for (int k = 0; k < NN; ++k) {
            const float a = Amat[i * NN + k];
            fxA = fmaf(a, x0A[k], fxA);
            fxB = fmaf(a, x0B[k], fxB);
        }
        LfA = fmaf(dhA[i], fxA, LfA);
        LfB = fmaf(dhB[i], fxB, LfB);
    }

#define GDECL(j) float gA##j = 0.0f, gB##j = 0.0f;
    FOR8(GDECL)
#undef GDECL
#pragma unroll
    for (int i = 0; i < NN; ++i) {
        const float da = dhA[i], db = dhB[i];
#define GACC(j) { const float w = Gmat[i * MM + j];                    \
                  gA##j = fmaf(da, w, gA##j);                          \
                  gB##j = fmaf(db, w, gB##j); }
        FOR8(GACC)
#undef GACC
    }

    const float c0A = fmaf(alphaA, hxA, LfA);
    const float c0B = fmaf(alphaB, hxB, LfB);

    // ---- QP per row (exact; all-scalar) ----
    const U8 uA = qp_solve(c0A,
        pvA[0].x, pvA[0].y, pvA[1].x, pvA[1].y,
        pvA[2].x, pvA[2].y, pvA[3].x, pvA[3].y,
        gA0, gA1, gA2, gA3, gA4, gA5, gA6, gA7);
    const U8 uB = qp_solve(c0B,
        pvB[0].x, pvB[0].y, pvB[1].x, pvB[1].y,
        pvB[2].x, pvB[2].y, pvB[3].x, pvB[3].y,
        gB0, gB1, gB2, gB3, gB4, gB5, gB6, gB7);

    // ---- stores ----
    float4* ovA = reinterpret_cast<float4*>(out + (size_t)rA * MM);
    ovA[0] = make_float4(uA.u0, uA.u1, uA.u2, uA.u3);
    ovA[1] = make_float4(uA.u4, uA.u5, uA.u6, uA.u7);
    if (vB) {
        float4* ovB = reinterpret_cast<float4*>(out + (size_t)rB * MM);
        ovB[0] = make_float4(uB.u0, uB.u1, uB.u2, uB.u3);
        ovB[1] = make_float4(uB.u4, uB.u5, uB.u6, uB.u7);
    }
}

extern "C" void kernel_launch(void* const* d_in, const int* in_sizes, int n_in,
                              void* d_out, int out_size, void* d_ws, size_t ws_size,
                              hipStream_t stream) {
    const float* x    = (const float*)d_in[0];
    const float* W1   = (const float*)d_in[1];
    const float* b1   = (const float*)d_in[2];
    const float* W21  = (const float*)d_in[3];
    const float* b21  = (const float*)d_in[4];
    const float* W22  = (const float*)d_in[5];
    const float* b22  = (const float*)d_in[6];
    const float* W31  = (const float*)d_in[7];
    const float* b31  = (const float*)d_in[8];
    const float* W32  = (const float*)d_in[9];
    const float* b32  = (const float*)d_in[10];
    const float* Amat = (const float*)d_in[11];
    const float* Gmat = (const float*)d_in[12];
    const float* mean = (const float*)d_in[13];
    const float* std_ = (const float*)d_in[14];

    const int B = in_sizes[0] / NN;
    const int rows_per_block = 512;             // 256 threads x 2 rows
    const int grid = (B + rows_per_block - 1) / rows_per_block;

    barrier_policy_kernel<<<grid, 256, 0, stream>>>(
        x, W1, b1, W21, b21, W22, b22, W31, b31, W32, b32,
        Amat, Gmat, mean, std_, (float*)d_out, B);
}

// Round 9
// 61.458 us; speedup vs baseline: 2.9843x; 2.9843x over previous
//
#include <hip/hip_runtime.h>

#define NN 8
#define MM 8
#define NH1 64
#define NH2 32

#define FOR8(OP) OP(0) OP(1) OP(2) OP(3) OP(4) OP(5) OP(6) OP(7)

typedef float v2f __attribute__((ext_vector_type(2)));

// =====================================================================
// Per-row computation. MLP in packed FP32 (v_pk_fma_f32) with float4
// weight loads at wave-uniform compile-time offsets (s_load-promotable
// when called from uniform control flow). Accumulation order per chain
// is bitwise-identical to the round-6 kernel.
// =====================================================================
__device__ __forceinline__ void compute_row(
    int row,
    const float* __restrict__ x_g,
    const float* __restrict__ W1,  const float* __restrict__ b1,
    const float* __restrict__ W21, const float* __restrict__ b21,
    const float* __restrict__ W22, const float* __restrict__ b22,
    const float* __restrict__ W31, const float* __restrict__ b31,
    const float* __restrict__ W32, const float* __restrict__ b32,
    const float* __restrict__ Amat, const float* __restrict__ Gmat,
    const float* __restrict__ mean, const float* __restrict__ std_,
    float* __restrict__ out)
{
    // ---- load x (vectorized, 32B/thread) ----
    float x[NN];
    {
        const float4* xv = reinterpret_cast<const float4*>(x_g + (size_t)row * NN);
        float4 a0 = xv[0], a1 = xv[1];
        x[0] = a0.x; x[1] = a0.y; x[2] = a0.z; x[3] = a0.w;
        x[4] = a1.x; x[5] = a1.y; x[6] = a1.z; x[7] = a1.w;
    }

    // ---- un-normalized state (float4 uniform loads) ----
    float x0[NN];
    {
        const float4 sd0 = ((const float4*)std_)[0], sd1 = ((const float4*)std_)[1];
        const float4 mn0 = ((const float4*)mean)[0], mn1 = ((const float4*)mean)[1];
        x0[0] = fmaf(x[0], sd0.x, mn0.x); x0[1] = fmaf(x[1], sd0.y, mn0.y);
        x0[2] = fmaf(x[2], sd0.z, mn0.z); x0[3] = fmaf(x[3], sd0.w, mn0.w);
        x0[4] = fmaf(x[4], sd1.x, mn1.x); x0[5] = fmaf(x[5], sd1.y, mn1.y);
        x0[6] = fmaf(x[6], sd1.z, mn1.z); x0[7] = fmaf(x[7], sd1.w, mn1.w);
    }

    // ---- layer 2 accumulators (init from biases, float4 loads) ----
    v2f a21[NH2 / 2], a22[NH2 / 2];
#pragma unroll
    for (int j4 = 0; j4 < NH2 / 4; ++j4) {
        const float4 i21 = ((const float4*)b21)[j4];
        const float4 i22 = ((const float4*)b22)[j4];
        a21[2 * j4]     = v2f{ i21.x, i21.y };
        a21[2 * j4 + 1] = v2f{ i21.z, i21.w };
        a22[2 * j4]     = v2f{ i22.x, i22.y };
        a22[2 * j4 + 1] = v2f{ i22.z, i22.w };
    }

    // ---- layer 1 fused into layer 2; 4 L1-channels per step ----
#pragma unroll
    for (int k4 = 0; k4 < NH1 / 4; ++k4) {
        // layer-1 quad h[4k4 .. 4k4+3]
        const float4 bq = ((const float4*)b1)[k4];
        v2f accLo = { bq.x, bq.y }, accHi = { bq.z, bq.w };
#pragma unroll
        for (int i = 0; i < NN; ++i) {
            const float4 w = *(const float4*)(W1 + i * NH1 + 4 * k4);
            const v2f xi = { x[i], x[i] };
            accLo = __builtin_elementwise_fma(xi, v2f{ w.x, w.y }, accLo);
            accHi = __builtin_elementwise_fma(xi, v2f{ w.z, w.w }, accHi);
        }
        const v2f zero2 = { 0.0f, 0.0f };
        const v2f hLo = __builtin_elementwise_max(accLo, zero2);  // h[4k4], h[4k4+1]
        const v2f hHi = __builtin_elementwise_max(accHi, zero2);  // h[4k4+2], h[4k4+3]

        // layer-2 accumulate, k-order = 4k4, 4k4+1, 4k4+2, 4k4+3
#define L2STEP(hbc, krow)                                                     \
        {                                                                     \
            const float4* w21q = (const float4*)(W21 + (krow) * NH2);         \
            const float4* w22q = (const float4*)(W22 + (krow) * NH2);         \
            _Pragma("unroll")                                                 \
            for (int j4 = 0; j4 < NH2 / 4; ++j4) {                            \
                const float4 wq1 = w21q[j4];                                  \
                const float4 wq2 = w22q[j4];                                  \
                a21[2*j4]   = __builtin_elementwise_fma(hbc, v2f{wq1.x, wq1.y}, a21[2*j4]);   \
                a21[2*j4+1] = __builtin_elementwise_fma(hbc, v2f{wq1.z, wq1.w}, a21[2*j4+1]); \
                a22[2*j4]   = __builtin_elementwise_fma(hbc, v2f{wq2.x, wq2.y}, a22[2*j4]);   \
                a22[2*j4+1] = __builtin_elementwise_fma(hbc, v2f{wq2.z, wq2.w}, a22[2*j4+1]); \
            }                                                                 \
        }
        { const v2f hb = hLo.xx; L2STEP(hb, 4 * k4); }
        { const v2f hb = hLo.yy; L2STEP(hb, 4 * k4 + 1); }
        { const v2f hb = hHi.xx; L2STEP(hb, 4 * k4 + 2); }
        { const v2f hb = hHi.yy; L2STEP(hb, 4 * k4 + 3); }
#undef L2STEP
    }
    {
        const v2f zero2 = { 0.0f, 0.0f };
#pragma unroll
        for (int j2 = 0; j2 < NH2 / 2; ++j2) {
            a21[j2] = __builtin_elementwise_max(a21[j2], zero2);
            a22[j2] = __builtin_elementwise_max(a22[j2], zero2);
        }
    }

    // ---- p-head (float4 weight loads), k-order ascending ----
    v2f pv[MM / 2];
    {
        const float4 ib0 = ((const float4*)b31)[0];
        const float4 ib1 = ((const float4*)b31)[1];
        pv[0] = v2f{ ib0.x, ib0.y }; pv[1] = v2f{ ib0.z, ib0.w };
        pv[2] = v2f{ ib1.x, ib1.y }; pv[3] = v2f{ ib1.z, ib1.w };
    }
#pragma unroll
    for (int k2 = 0; k2 < NH2 / 2; ++k2) {
#define PSTEP(hbc, krow)                                                      \
        {                                                                     \
            const float4* w31q = (const float4*)(W31 + (krow) * MM);          \
            _Pragma("unroll")                                                 \
            for (int j4 = 0; j4 < MM / 4; ++j4) {                             \
                const float4 wq = w31q[j4];                                   \
                pv[2*j4]   = __builtin_elementwise_fma(hbc, v2f{wq.x, wq.y}, pv[2*j4]);   \
                pv[2*j4+1] = __builtin_elementwise_fma(hbc, v2f{wq.z, wq.w}, pv[2*j4+1]); \
            }                                                                 \
        }
        { const v2f hb = a21[k2].xx; PSTEP(hb, 2 * k2); }
        { const v2f hb = a21[k2].yy; PSTEP(hb, 2 * k2 + 1); }
#undef PSTEP
    }

    // ---- alpha-head: scalar chain, v2f weight loads ----
    float s = b32[0];
#pragma unroll
    for (int k2 = 0; k2 < NH2 / 2; ++k2) {
        const v2f w2 = *(const v2f*)(W32 + 2 * k2);
        s = fmaf(a22[k2].x, w2.x, s);
        s = fmaf(a22[k2].y, w2.y, s);
    }
    const float alphax = 4.0f / (1.0f + __expf(-s));

    // ---- barrier terms ----
    float hx = 16.0f;
#pragma unroll
    for (int i = 0; i < NN; ++i) hx = fmaf(-x0[i], x0[i], hx);

    float dh[NN];
#pragma unroll
    for (int i = 0; i < NN; ++i) dh[i] = -2.0f * x0[i];

    float Lfhx = 0.0f;
#pragma unroll
    for (int i = 0; i < NN; ++i) {
        const float4 aq0 = *(const float4*)(Amat + i * NN);
        const float4 aq1 = *(const float4*)(Amat + i * NN + 4);
        float fx = 0.0f;
        fx = fmaf(aq0.x, x0[0], fx); fx = fmaf(aq0.y, x0[1], fx);
        fx = fmaf(aq0.z, x0[2], fx); fx = fmaf(aq0.w, x0[3], fx);
        fx = fmaf(aq1.x, x0[4], fx); fx = fmaf(aq1.y, x0[5], fx);
        fx = fmaf(aq1.z, x0[6], fx); fx = fmaf(aq1.w, x0[7], fx);
        Lfhx = fmaf(dh[i], fx, Lfhx);
    }

    // g[j] accumulates over i ascending (same chains as round 6)
#define GDECL(j) float g##j = 0.0f;
    FOR8(GDECL)
#undef GDECL
#pragma unroll
    for (int i = 0; i < NN; ++i) {
        const float4 gq0 = *(const float4*)(Gmat + i * MM);
        const float4 gq1 = *(const float4*)(Gmat + i * MM + 4);
        const float da = dh[i];
        g0 = fmaf(da, gq0.x, g0); g1 = fmaf(da, gq0.y, g1);
        g2 = fmaf(da, gq0.z, g2); g3 = fmaf(da, gq0.w, g3);
        g4 = fmaf(da, gq1.x, g4); g5 = fmaf(da, gq1.y, g5);
        g6 = fmaf(da, gq1.z, g6); g7 = fmaf(da, gq1.w, g7);
    }

    const float c0 = fmaf(alphax, hx, Lfhx);

    // =====================================================================
    // QP via exact piecewise-linear root isolation — fully scalarized.
    // =====================================================================
#define DECL_PG(j) const float p##j = (j & 1) ? pv[j >> 1].y : pv[j >> 1].x;
    FOR8(DECL_PG)
#undef DECL_PG

    auto c_of = [&](float lam) -> float {
        float c = c0;
#define CTERM(j) { float u = fmaf(lam, g##j, -p##j);                  \
                   u = fminf(fmaxf(u, -1.0f), 1.0f);                  \
                   c = fmaf(g##j, u, c); }
        FOR8(CTERM)
#undef CTERM
        return c;
    };

    const bool viol = (c_of(0.0f) < 0.0f);

    const float BIGR = 3.0e38f;         // sentinel: no right bracket found
    float lamL = 0.0f, lamR = BIGR;
#define BP(j) {                                                        \
        const float rg = __builtin_amdgcn_rcpf(g##j);                  \
        const float bpa = (p##j - 1.0f) * rg;                          \
        const float bpb = (p##j + 1.0f) * rg;                          \
        const float ca = c_of(bpa);                                    \
        const float cb = c_of(bpb);                                    \
        lamL = (bpa > 0.0f && ca <  0.0f && bpa > lamL) ? bpa : lamL;  \
        lamR = (bpa > 0.0f && ca >= 0.0f && bpa < lamR) ? bpa : lamR;  \
        lamL = (bpb > 0.0f && cb <  0.0f && bpb > lamL) ? bpb : lamL;  \
        lamR = (bpb > 0.0f && cb >= 0.0f && bpb < lamR) ? bpb : lamR;  \
    }
    FOR8(BP)
#undef BP

    // lam_t strictly inside the root's segment (same segment the reference's
    // bisection lands in). Infeasible => classify at the capped bracket 2^40.
    const bool infeas = (lamR == BIGR);
    float lam_t = infeas ? 1.099511627776e12f : 0.5f * (lamL + lamR);
    lam_t = viol ? lam_t : 0.0f;

    // frozen active set -> closed-form lambda (exact KKT refinement, == ref)
    float denom = 0.0f, num = c0;
#define ASET(j)                                                        \
    const float ur##j = fmaf(lam_t, g##j, -p##j);                      \
    const bool lo##j = (ur##j <= -1.0f);                               \
    const bool hi##j = (ur##j >=  1.0f);                               \
    denom += (!(lo##j || hi##j)) ? g##j * g##j : 0.0f;                 \
    num   += lo##j ? -g##j : (hi##j ? g##j : -g##j * p##j);
    FOR8(ASET)
#undef ASET

    const float lam = viol ? (-num / (denom + 1e-12f)) : 0.0f;

#define UOUT(j) const float uo##j =                                    \
    lo##j ? -1.0f : (hi##j ? 1.0f : fmaf(lam, g##j, -p##j));
    FOR8(UOUT)
#undef UOUT

    // ---- store (vectorized) ----
    float4* ov = reinterpret_cast<float4*>(out + (size_t)row * MM);
    ov[0] = make_float4(uo0, uo1, uo2, uo3);
    ov[1] = make_float4(uo4, uo5, uo6, uo7);
}

#define ARGS_DECL                                                       \
    const float* __restrict__ x_g,                                      \
    const float* __restrict__ W1,  const float* __restrict__ b1,        \
    const float* __restrict__ W21, const float* __restrict__ b21,       \
    const float* __restrict__ W22, const float* __restrict__ b22,       \
    const float* __restrict__ W31, const float* __restrict__ b31,       \
    const float* __restrict__ W32, const float* __restrict__ b32,       \
    const float* __restrict__ Amat, const float* __restrict__ Gmat,     \
    const float* __restrict__ mean, const float* __restrict__ std_,    \
    float* __restrict__ out
#define ARGS_PASS x_g, W1, b1, W21, b21, W22, b22, W31, b31, W32, b32, \
                  Amat, Gmat, mean, std_, out

// Branch-free kernel: uniform control flow from entry -> weight loads are
// provably uniform + noclobber -> SMEM (s_load) promotion eligible.
__global__ __launch_bounds__(256, 2) void barrier_policy_clean(ARGS_DECL)
{
    const int row = blockIdx.x * 256 + threadIdx.x;
    compute_row(row, ARGS_PASS);
}

// Guarded fallback for B % 256 != 0.
__global__ __launch_bounds__(256, 2) void barrier_policy_guard(ARGS_DECL, int B)
{
    const int row = blockIdx.x * 256 + threadIdx.x;
    if (row < B) compute_row(row, ARGS_PASS);
}

extern "C" void kernel_launch(void* const* d_in, const int* in_sizes, int n_in,
                              void* d_out, int out_size, void* d_ws, size_t ws_size,
                              hipStream_t stream) {
    const float* x    = (const float*)d_in[0];
    const float* W1   = (const float*)d_in[1];
    const float* b1   = (const float*)d_in[2];
    const float* W21  = (const float*)d_in[3];
    const float* b21  = (const float*)d_in[4];
    const float* W22  = (const float*)d_in[5];
    const float* b22  = (const float*)d_in[6];
    const float* W31  = (const float*)d_in[7];
    const float* b31  = (const float*)d_in[8];
    const float* W32  = (const float*)d_in[9];
    const float* b32  = (const float*)d_in[10];
    const float* Amat = (const float*)d_in[11];
    const float* Gmat = (const float*)d_in[12];
    const float* mean = (const float*)d_in[13];
    const float* std_ = (const float*)d_in[14];
    float* out = (float*)d_out;

    const int B = in_sizes[0] / NN;
    if (B % 256 == 0) {
        barrier_policy_clean<<<B / 256, 256, 0, stream>>>(
            x, W1, b1, W21, b21, W22, b22, W31, b31, W32, b32,
            Amat, Gmat, mean, std_, out);
    } else {
        barrier_policy_guard<<<(B + 255) / 256, 256, 0, stream>>>(
            x, W1, b1, W21, b21, W22, b22, W31, b31, W32, b32,
            Amat, Gmat, mean, std_, out, B);
    }
}

// Round 10
// 50.751 us; speedup vs baseline: 3.6139x; 1.2110x over previous
//
#include <hip/hip_runtime.h>

#define NN 8
#define MM 8
#define NH1 64
#define NH2 32

#define FOR8(OP) OP(0) OP(1) OP(2) OP(3) OP(4) OP(5) OP(6) OP(7)

typedef float v2f  __attribute__((ext_vector_type(2)));
typedef float sf16 __attribute__((ext_vector_type(16)));

// Two s_load_dwordx16 (64B each) + one waitcnt, all inside one asm:
// latency paid once, outputs live in SGPRs, dataflow-safe (use depends on
// asm outputs). Early-clobber: pointer operand is read after first write.
#define SLOAD2X16(d0, d1, ptr)                                         \
    asm("s_load_dwordx16 %0, %2, 0x0\n\t"                              \
        "s_load_dwordx16 %1, %2, 0x40\n\t"                             \
        "s_waitcnt lgkmcnt(0)"                                         \
        : "=&s"(d0), "=&s"(d1) : "s"(ptr))

#define SLOAD1X16(d0, ptr)                                             \
    asm("s_load_dwordx16 %0, %1, 0x0\n\t"                              \
        "s_waitcnt lgkmcnt(0)"                                         \
        : "=&s"(d0) : "s"(ptr))

__device__ __forceinline__ void compute_row(
    int row,
    const float* __restrict__ x_g,
    const float* __restrict__ W1,  const float* __restrict__ b1,
    const float* __restrict__ W21, const float* __restrict__ b21,
    const float* __restrict__ W22, const float* __restrict__ b22,
    const float* __restrict__ W31, const float* __restrict__ b31,
    const float* __restrict__ W32, const float* __restrict__ b32,
    const float* __restrict__ Amat, const float* __restrict__ Gmat,
    const float* __restrict__ mean, const float* __restrict__ std_,
    float* __restrict__ out)
{
    // ---- load x (per-lane, vectorized) ----
    float x[NN];
    {
        const float4* xv = reinterpret_cast<const float4*>(x_g + (size_t)row * NN);
        float4 a0 = xv[0], a1 = xv[1];
        x[0] = a0.x; x[1] = a0.y; x[2] = a0.z; x[3] = a0.w;
        x[4] = a1.x; x[5] = a1.y; x[6] = a1.z; x[7] = a1.w;
    }

    // ---- un-normalized state ----
    float x0[NN];
    {
        const float4 sd0 = ((const float4*)std_)[0], sd1 = ((const float4*)std_)[1];
        const float4 mn0 = ((const float4*)mean)[0], mn1 = ((const float4*)mean)[1];
        x0[0] = fmaf(x[0], sd0.x, mn0.x); x0[1] = fmaf(x[1], sd0.y, mn0.y);
        x0[2] = fmaf(x[2], sd0.z, mn0.z); x0[3] = fmaf(x[3], sd0.w, mn0.w);
        x0[4] = fmaf(x[4], sd1.x, mn1.x); x0[5] = fmaf(x[5], sd1.y, mn1.y);
        x0[6] = fmaf(x[6], sd1.z, mn1.z); x0[7] = fmaf(x[7], sd1.w, mn1.w);
    }

    // =====================================================================
    // Layer 1 (unfused): h pairs, chain order identical to round 6
    // (each pair inits from b1 then accumulates i = 0..7 ascending).
    // Weights stream through the SCALAR pipe (s_load_dwordx16).
    // =====================================================================
    v2f hv[NH1 / 2];
#pragma unroll
    for (int j2 = 0; j2 < NH1 / 2; ++j2) hv[j2] = *(const v2f*)(b1 + 2 * j2);

#pragma unroll
    for (int i = 0; i < NN; ++i) {
        const v2f xi = { x[i], x[i] };
        {
            sf16 r0, r1;
            SLOAD2X16(r0, r1, W1 + i * NH1);        // W1[i][0..31]
#pragma unroll
            for (int j2 = 0; j2 < 8; ++j2)
                hv[j2]     = __builtin_elementwise_fma(xi, v2f{ r0[2*j2], r0[2*j2+1] }, hv[j2]);
#pragma unroll
            for (int j2 = 0; j2 < 8; ++j2)
                hv[8 + j2] = __builtin_elementwise_fma(xi, v2f{ r1[2*j2], r1[2*j2+1] }, hv[8 + j2]);
        }
        {
            sf16 r2, r3;
            SLOAD2X16(r2, r3, W1 + i * NH1 + 32);   // W1[i][32..63]
#pragma unroll
            for (int j2 = 0; j2 < 8; ++j2)
                hv[16 + j2] = __builtin_elementwise_fma(xi, v2f{ r2[2*j2], r2[2*j2+1] }, hv[16 + j2]);
#pragma unroll
            for (int j2 = 0; j2 < 8; ++j2)
                hv[24 + j2] = __builtin_elementwise_fma(xi, v2f{ r3[2*j2], r3[2*j2+1] }, hv[24 + j2]);
        }
    }
    {
        const v2f zero2 = { 0.0f, 0.0f };
#pragma unroll
        for (int j2 = 0; j2 < NH1 / 2; ++j2) hv[j2] = __builtin_elementwise_max(hv[j2], zero2);
    }

    // =====================================================================
    // Layer 2: per k, a21 (j ascending) then a22 (j ascending) — same
    // chains/order as round 6. W21/W22 rows via scalar pipe.
    // =====================================================================
    v2f a21[NH2 / 2], a22[NH2 / 2];
#pragma unroll
    for (int j2 = 0; j2 < NH2 / 2; ++j2) {
        a21[j2] = *(const v2f*)(b21 + 2 * j2);
        a22[j2] = *(const v2f*)(b22 + 2 * j2);
    }

#pragma unroll
    for (int k = 0; k < NH1; ++k) {
        const v2f hb = (k & 1) ? hv[k >> 1].yy : hv[k >> 1].xx;
        {
            sf16 q0, q1;
            SLOAD2X16(q0, q1, W21 + k * NH2);       // W21[k][0..31]
#pragma unroll
            for (int j2 = 0; j2 < 8; ++j2)
                a21[j2]     = __builtin_elementwise_fma(hb, v2f{ q0[2*j2], q0[2*j2+1] }, a21[j2]);
#pragma unroll
            for (int j2 = 0; j2 < 8; ++j2)
                a21[8 + j2] = __builtin_elementwise_fma(hb, v2f{ q1[2*j2], q1[2*j2+1] }, a21[8 + j2]);
        }
        {
            sf16 q2, q3;
            SLOAD2X16(q2, q3, W22 + k * NH2);       // W22[k][0..31]
#pragma unroll
            for (int j2 = 0; j2 < 8; ++j2)
                a22[j2]     = __builtin_elementwise_fma(hb, v2f{ q2[2*j2], q2[2*j2+1] }, a22[j2]);
#pragma unroll
            for (int j2 = 0; j2 < 8; ++j2)
                a22[8 + j2] = __builtin_elementwise_fma(hb, v2f{ q3[2*j2], q3[2*j2+1] }, a22[8 + j2]);
        }
    }
    {
        const v2f zero2 = { 0.0f, 0.0f };
#pragma unroll
        for (int j2 = 0; j2 < NH2 / 2; ++j2) {
            a21[j2] = __builtin_elementwise_max(a21[j2], zero2);
            a22[j2] = __builtin_elementwise_max(a22[j2], zero2);
        }
    }

    // ---- p-head: per k2 one x16 = rows 2k2,2k2+1 of W31 (scalar pipe) ----
    v2f pv[MM / 2];
#pragma unroll
    for (int j2 = 0; j2 < MM / 2; ++j2) pv[j2] = *(const v2f*)(b31 + 2 * j2);
#pragma unroll
    for (int k2 = 0; k2 < NH2 / 2; ++k2) {
        sf16 w;
        SLOAD1X16(w, W31 + (2 * k2) * MM);
        const v2f ha = a21[k2].xx, hb2 = a21[k2].yy;
#pragma unroll
        for (int j2 = 0; j2 < 4; ++j2)
            pv[j2] = __builtin_elementwise_fma(ha,  v2f{ w[2*j2],     w[2*j2+1]     }, pv[j2]);
#pragma unroll
        for (int j2 = 0; j2 < 4; ++j2)
            pv[j2] = __builtin_elementwise_fma(hb2, v2f{ w[8 + 2*j2], w[8 + 2*j2+1] }, pv[j2]);
    }

    // ---- alpha-head: scalar chain (same order as round 6) ----
    float s = b32[0];
#pragma unroll
    for (int k2 = 0; k2 < NH2 / 2; ++k2) {
        const v2f w2 = *(const v2f*)(W32 + 2 * k2);
        s = fmaf(a22[k2].x, w2.x, s);
        s = fmaf(a22[k2].y, w2.y, s);
    }
    const float alphax = 4.0f / (1.0f + __expf(-s));

    // ---- barrier terms ----
    float hx = 16.0f;
#pragma unroll
    for (int i = 0; i < NN; ++i) hx = fmaf(-x0[i], x0[i], hx);

    float dh[NN];
#pragma unroll
    for (int i = 0; i < NN; ++i) dh[i] = -2.0f * x0[i];

    float Lfhx = 0.0f;
#pragma unroll
    for (int i = 0; i < NN; ++i) {
        const float4 aq0 = *(const float4*)(Amat + i * NN);
        const float4 aq1 = *(const float4*)(Amat + i * NN + 4);
        float fx = 0.0f;
        fx = fmaf(aq0.x, x0[0], fx); fx = fmaf(aq0.y, x0[1], fx);
        fx = fmaf(aq0.z, x0[2], fx); fx = fmaf(aq0.w, x0[3], fx);
        fx = fmaf(aq1.x, x0[4], fx); fx = fmaf(aq1.y, x0[5], fx);
        fx = fmaf(aq1.z, x0[6], fx); fx = fmaf(aq1.w, x0[7], fx);
        Lfhx = fmaf(dh[i], fx, Lfhx);
    }

#define GDECL(j) float g##j = 0.0f;
    FOR8(GDECL)
#undef GDECL
#pragma unroll
    for (int i = 0; i < NN; ++i) {
        const float4 gq0 = *(const float4*)(Gmat + i * MM);
        const float4 gq1 = *(const float4*)(Gmat + i * MM + 4);
        const float da = dh[i];
        g0 = fmaf(da, gq0.x, g0); g1 = fmaf(da, gq0.y, g1);
        g2 = fmaf(da, gq0.z, g2); g3 = fmaf(da, gq0.w, g3);
        g4 = fmaf(da, gq1.x, g4); g5 = fmaf(da, gq1.y, g5);
        g6 = fmaf(da, gq1.z, g6); g7 = fmaf(da, gq1.w, g7);
    }

    const float c0 = fmaf(alphax, hx, Lfhx);

    // =====================================================================
    // QP via exact piecewise-linear root isolation — fully scalarized.
    // =====================================================================
#define DECL_PG(j) const float p##j = (j & 1) ? pv[j >> 1].y : pv[j >> 1].x;
    FOR8(DECL_PG)
#undef DECL_PG

    auto c_of = [&](float lam) -> float {
        float c = c0;
#define CTERM(j) { float u = fmaf(lam, g##j, -p##j);                  \
                   u = fminf(fmaxf(u, -1.0f), 1.0f);                  \
                   c = fmaf(g##j, u, c); }
        FOR8(CTERM)
#undef CTERM
        return c;
    };

    const bool viol = (c_of(0.0f) < 0.0f);

    const float BIGR = 3.0e38f;         // sentinel: no right bracket found
    float lamL = 0.0f, lamR = BIGR;
#define BP(j) {                                                        \
        const float rg = __builtin_amdgcn_rcpf(g##j);                  \
        const float bpa = (p##j - 1.0f) * rg;                          \
        const float bpb = (p##j + 1.0f) * rg;                          \
        const float ca = c_of(bpa);                                    \
        const float cb = c_of(bpb);                                    \
        lamL = (bpa > 0.0f && ca <  0.0f && bpa > lamL) ? bpa : lamL;  \
        lamR = (bpa > 0.0f && ca >= 0.0f && bpa < lamR) ? bpa : lamR;  \
        lamL = (bpb > 0.0f && cb <  0.0f && bpb > lamL) ? bpb : lamL;  \
        lamR = (bpb > 0.0f && cb >= 0.0f && bpb < lamR) ? bpb : lamR;  \
    }
    FOR8(BP)
#undef BP

    const bool infeas = (lamR == BIGR);
    float lam_t = infeas ? 1.099511627776e12f : 0.5f * (lamL + lamR);
    lam_t = viol ? lam_t : 0.0f;

    float denom = 0.0f, num = c0;
#define ASET(j)                                                        \
    const float ur##j = fmaf(lam_t, g##j, -p##j);                      \
    const bool lo##j = (ur##j <= -1.0f);                               \
    const bool hi##j = (ur##j >=  1.0f);                               \
    denom += (!(lo##j || hi##j)) ? g##j * g##j : 0.0f;                 \
    num   += lo##j ? -g##j : (hi##j ? g##j : -g##j * p##j);
    FOR8(ASET)
#undef ASET

    const float lam = viol ? (-num / (denom + 1e-12f)) : 0.0f;

#define UOUT(j) const float uo##j =                                    \
    lo##j ? -1.0f : (hi##j ? 1.0f : fmaf(lam, g##j, -p##j));
    FOR8(UOUT)
#undef UOUT

    float4* ov = reinterpret_cast<float4*>(out + (size_t)row * MM);
    ov[0] = make_float4(uo0, uo1, uo2, uo3);
    ov[1] = make_float4(uo4, uo5, uo6, uo7);
}

#define ARGS_DECL                                                       \
    const float* __restrict__ x_g,                                      \
    const float* __restrict__ W1,  const float* __restrict__ b1,        \
    const float* __restrict__ W21, const float* __restrict__ b21,       \
    const float* __restrict__ W22, const float* __restrict__ b22,       \
    const float* __restrict__ W31, const float* __restrict__ b31,       \
    const float* __restrict__ W32, const float* __restrict__ b32,       \
    const float* __restrict__ Amat, const float* __restrict__ Gmat,     \
    const float* __restrict__ mean, const float* __restrict__ std_,    \
    float* __restrict__ out
#define ARGS_PASS x_g, W1, b1, W21, b21, W22, b22, W31, b31, W32, b32, \
                  Amat, Gmat, mean, std_, out

__global__ __launch_bounds__(256, 2) void barrier_policy_clean(ARGS_DECL)
{
    const int row = blockIdx.x * 256 + threadIdx.x;
    compute_row(row, ARGS_PASS);
}

__global__ __launch_bounds__(256, 2) void barrier_policy_guard(ARGS_DECL, int B)
{
    const int row = blockIdx.x * 256 + threadIdx.x;
    if (row < B) compute_row(row, ARGS_PASS);
}

extern "C" void kernel_launch(void* const* d_in, const int* in_sizes, int n_in,
                              void* d_out, int out_size, void* d_ws, size_t ws_size,
                              hipStream_t stream) {
    const float* x    = (const float*)d_in[0];
    const float* W1   = (const float*)d_in[1];
    const float* b1   = (const float*)d_in[2];
    const float* W21  = (const float*)d_in[3];
    const float* b21  = (const float*)d_in[4];
    const float* W22  = (const float*)d_in[5];
    const float* b22  = (const float*)d_in[6];
    const float* W31  = (const float*)d_in[7];
    const float* b31  = (const float*)d_in[8];
    const float* W32  = (const float*)d_in[9];
    const float* b32  = (const float*)d_in[10];
    const float* Amat = (const float*)d_in[11];
    const float* Gmat = (const float*)d_in[12];
    const float* mean = (const float*)d_in[13];
    const float* std_ = (const float*)d_in[14];
    float* out = (float*)d_out;

    const int B = in_sizes[0] / NN;
    if (B % 256 == 0) {
        barrier_policy_clean<<<B / 256, 256, 0, stream>>>(
            x, W1, b1, W21, b21, W22, b22, W31, b31, W32, b32,
            Amat, Gmat, mean, std_, out);
    } else {
        barrier_policy_guard<<<(B + 255) / 256, 256, 0, stream>>>(
            x, W1, b1, W21, b21, W22, b22, W31, b31, W32, b32,
            Amat, Gmat, mean, std_, out, B);
    }
}

// Round 12
// 43.542 us; speedup vs baseline: 4.2122x; 1.1655x over previous
//
#include <hip/hip_runtime.h>

#define NN 8
#define MM 8
#define NH1 64
#define NH2 32

#define FOR8(OP) OP(0) OP(1) OP(2) OP(3) OP(4) OP(5) OP(6) OP(7)

typedef float v2f  __attribute__((ext_vector_type(2)));
typedef float sf16 __attribute__((ext_vector_type(16)));

// ---- scalar-pipe streaming: split ISSUE (no wait) / WAIT (tied to data) ----
// ISSUE: two s_load_dwordx16 (128B) at base + byte-imm. No wait -> loads fly
// under the following VALU block. volatile pins placement.
#define S_ISSUE2(d0, d1, base, imm)                                    \
    asm volatile("s_load_dwordx16 %0, %2, %c3\n\t"                     \
                 "s_load_dwordx16 %1, %2, %c4"                         \
                 : "=&s"(d0), "=&s"(d1)                                \
                 : "s"(base), "n"(imm), "n"((imm) + 64))

#define S_ISSUE1(d0, base, imm)                                        \
    asm volatile("s_load_dwordx16 %0, %1, %c2"                         \
                 : "=&s"(d0) : "s"(base), "n"(imm))

// WAIT: lgkmcnt(0) with the buffers as in/out operands -> consumers of the
// buffer are dataflow-ordered AFTER the wait (rule-#18-safe, no sched hoist).
#define S_WAIT2(d0, d1)                                                \
    asm volatile("s_waitcnt lgkmcnt(0)" : "+s"(d0), "+s"(d1))

#define S_WAIT1(d0)                                                    \
    asm volatile("s_waitcnt lgkmcnt(0)" : "+s"(d0))

// acc += w * xi, packed f32. w is the ONE scalar (SGPR-pair) operand folded
// directly into VOP3P src0 -> zero v_mov staging.
#define PKFMA(acc, w, xi)                                              \
    asm("v_pk_fma_f32 %0, %1, %2, %0" : "+v"(acc) : "s"(w), "v"(xi))

__device__ __forceinline__ void compute_row(
    int row,
    const float* __restrict__ x_g,
    const float* __restrict__ W1,  const float* __restrict__ b1,
    const float* __restrict__ W21, const float* __restrict__ b21,
    const float* __restrict__ W22, const float* __restrict__ b22,
    const float* __restrict__ W31, const float* __restrict__ b31,
    const float* __restrict__ W32, const float* __restrict__ b32,
    const float* __restrict__ Amat, const float* __restrict__ Gmat,
    const float* __restrict__ mean, const float* __restrict__ std_,
    float* __restrict__ out)
{
    // ---- load x (per-lane, vectorized) ----
    float x[NN];
    {
        const float4* xv = reinterpret_cast<const float4*>(x_g + (size_t)row * NN);
        float4 a0 = xv[0], a1 = xv[1];
        x[0] = a0.x; x[1] = a0.y; x[2] = a0.z; x[3] = a0.w;
        x[4] = a1.x; x[5] = a1.y; x[6] = a1.z; x[7] = a1.w;
    }

    // ---- un-normalized state ----
    float x0[NN];
    {
        const float4 sd0 = ((const float4*)std_)[0], sd1 = ((const float4*)std_)[1];
        const float4 mn0 = ((const float4*)mean)[0], mn1 = ((const float4*)mean)[1];
        x0[0] = fmaf(x[0], sd0.x, mn0.x); x0[1] = fmaf(x[1], sd0.y, mn0.y);
        x0[2] = fmaf(x[2], sd0.z, mn0.z); x0[3] = fmaf(x[3], sd0.w, mn0.w);
        x0[4] = fmaf(x[4], sd1.x, mn1.x); x0[5] = fmaf(x[5], sd1.y, mn1.y);
        x0[6] = fmaf(x[6], sd1.z, mn1.z); x0[7] = fmaf(x[7], sd1.w, mn1.w);
    }

    // =====================================================================
    // Layer 1: 16 units of 128B (unit u: row i = u>>1, half h = u&1).
    // Depth-1 pipelined scalar stream; chain order per hv[j] = i ascending
    // (identical to round 6/10).
    // =====================================================================
    v2f hv[NH1 / 2];
#pragma unroll
    for (int j2 = 0; j2 < NH1 / 2; ++j2) hv[j2] = *(const v2f*)(b1 + 2 * j2);

    {
        sf16 rA0, rA1, rB0, rB1;
        S_ISSUE2(rA0, rA1, W1, 0);
        S_WAIT2(rA0, rA1);
#pragma unroll
        for (int u = 0; u < 16; ++u) {
            const int i = u >> 1, hh = u & 1;
            const v2f xi = { x[i], x[i] };
            if ((u & 1) == 0) {
                if (u + 1 < 16) S_ISSUE2(rB0, rB1, W1, (u + 1) * 128);
#pragma unroll
                for (int j2 = 0; j2 < 8; ++j2) { const v2f w = { rA0[2*j2], rA0[2*j2+1] }; PKFMA(hv[hh*16 + j2], w, xi); }
#pragma unroll
                for (int j2 = 0; j2 < 8; ++j2) { const v2f w = { rA1[2*j2], rA1[2*j2+1] }; PKFMA(hv[hh*16 + 8 + j2], w, xi); }
                if (u + 1 < 16) S_WAIT2(rB0, rB1);
            } else {
                if (u + 1 < 16) S_ISSUE2(rA0, rA1, W1, (u + 1) * 128);
#pragma unroll
                for (int j2 = 0; j2 < 8; ++j2) { const v2f w = { rB0[2*j2], rB0[2*j2+1] }; PKFMA(hv[hh*16 + j2], w, xi); }
#pragma unroll
                for (int j2 = 0; j2 < 8; ++j2) { const v2f w = { rB1[2*j2], rB1[2*j2+1] }; PKFMA(hv[hh*16 + 8 + j2], w, xi); }
                if (u + 1 < 16) S_WAIT2(rA0, rA1);
            }
        }
    }
    {
        const v2f zero2 = { 0.0f, 0.0f };
#pragma unroll
        for (int j2 = 0; j2 < NH1 / 2; ++j2) hv[j2] = __builtin_elementwise_max(hv[j2], zero2);
    }

    // =====================================================================
    // Layer 2, two pipelined passes (a21 over W21, then a22 over W22).
    // Chain per accumulator = k ascending -> bitwise-identical to round 6.
    // =====================================================================
    v2f a21[NH2 / 2], a22[NH2 / 2];
#pragma unroll
    for (int j2 = 0; j2 < NH2 / 2; ++j2) {
        a21[j2] = *(const v2f*)(b21 + 2 * j2);
        a22[j2] = *(const v2f*)(b22 + 2 * j2);
    }

#define L2PASS(ACC, WBASE)                                                     \
    {                                                                          \
        sf16 qA0, qA1, qB0, qB1;                                               \
        S_ISSUE2(qA0, qA1, WBASE, 0);                                          \
        S_WAIT2(qA0, qA1);                                                     \
        _Pragma("unroll")                                                      \
        for (int k = 0; k < NH1; ++k) {                                        \
            const v2f hb = (k & 1) ? hv[k >> 1].yy : hv[k >> 1].xx;            \
            if ((k & 1) == 0) {                                                \
                if (k + 1 < NH1) S_ISSUE2(qB0, qB1, WBASE, (k + 1) * 128);     \
                _Pragma("unroll")                                              \
                for (int j2 = 0; j2 < 8; ++j2) { const v2f w = { qA0[2*j2], qA0[2*j2+1] }; PKFMA(ACC[j2], w, hb); } \
                _Pragma("unroll")                                              \
                for (int j2 = 0; j2 < 8; ++j2) { const v2f w = { qA1[2*j2], qA1[2*j2+1] }; PKFMA(ACC[8 + j2], w, hb); } \
                if (k + 1 < NH1) S_WAIT2(qB0, qB1);                            \
            } else {                                                           \
                if (k + 1 < NH1) S_ISSUE2(qA0, qA1, WBASE, (k + 1) * 128);     \
                _Pragma("unroll")                                              \
                for (int j2 = 0; j2 < 8; ++j2) { const v2f w = { qB0[2*j2], qB0[2*j2+1] }; PKFMA(ACC[j2], w, hb); } \
                _Pragma("unroll")                                              \
                for (int j2 = 0; j2 < 8; ++j2) { const v2f w = { qB1[2*j2], qB1[2*j2+1] }; PKFMA(ACC[8 + j2], w, hb); } \
                if (k + 1 < NH1) S_WAIT2(qA0, qA1);                            \
            }                                                                  \
        }                                                                      \
    }

    L2PASS(a21, W21)
    L2PASS(a22, W22)
#undef L2PASS

    {
        const v2f zero2 = { 0.0f, 0.0f };
#pragma unroll
        for (int j2 = 0; j2 < NH2 / 2; ++j2) {
            a21[j2] = __builtin_elementwise_max(a21[j2], zero2);
            a22[j2] = __builtin_elementwise_max(a22[j2], zero2);
        }
    }

    // ---- alpha-head weights: issue early, consumed after p-head ----
    sf16 wA0, wA1;
    S_ISSUE2(wA0, wA1, W32, 0);

    // ---- p-head: 16 pipelined units of one x16 (rows 2k2, 2k2+1) ----
    // (round-11 bug: guards said k2+1<8, starving units 8..15 of fresh
    //  weights -> absmax 2.0. Correct bound is k2+1<16.)
    v2f pv[MM / 2];
#pragma unroll
    for (int j2 = 0; j2 < MM / 2; ++j2) pv[j2] = *(const v2f*)(b31 + 2 * j2);
    {
        sf16 pA, pB;
        S_ISSUE1(pA, W31, 0);
        S_WAIT1(pA);
#pragma unroll
        for (int k2 = 0; k2 < NH2 / 2; ++k2) {
            const v2f ha = a21[k2].xx, hb2 = a21[k2].yy;
            if ((k2 & 1) == 0) {
                if (k2 + 1 < 16) S_ISSUE1(pB, W31, (k2 + 1) * 64);
#pragma unroll
                for (int j2 = 0; j2 < 4; ++j2) { const v2f w = { pA[2*j2], pA[2*j2+1] }; PKFMA(pv[j2], w, ha); }
#pragma unroll
                for (int j2 = 0; j2 < 4; ++j2) { const v2f w = { pA[8 + 2*j2], pA[8 + 2*j2+1] }; PKFMA(pv[j2], w, hb2); }
                if (k2 + 1 < 16) S_WAIT1(pB);
            } else {
                if (k2 + 1 < 16) S_ISSUE1(pA, W31, (k2 + 1) * 64);
#pragma unroll
                for (int j2 = 0; j2 < 4; ++j2) { const v2f w = { pB[2*j2], pB[2*j2+1] }; PKFMA(pv[j2], w, ha); }
#pragma unroll
                for (int j2 = 0; j2 < 4; ++j2) { const v2f w = { pB[8 + 2*j2], pB[8 + 2*j2+1] }; PKFMA(pv[j2], w, hb2); }
                if (k2 + 1 < 16) S_WAIT1(pA);
            }
        }
    }

    // ---- alpha-head: serial scalar chain, k ascending (same as round 6) ----
    S_WAIT2(wA0, wA1);
    float s = b32[0];
#pragma unroll
    for (int k = 0; k < 16; ++k)
        s = fmaf((k & 1) ? a22[k >> 1].y : a22[k >> 1].x, wA0[k], s);
#pragma unroll
    for (int k = 16; k < 32; ++k)
        s = fmaf((k & 1) ? a22[k >> 1].y : a22[k >> 1].x, wA1[k - 16], s);
    const float alphax = 4.0f / (1.0f + __expf(-s));

    // ---- barrier terms ----
    float hx = 16.0f;
#pragma unroll
    for (int i = 0; i < NN; ++i) hx = fmaf(-x0[i], x0[i], hx);

    float dh[NN];
#pragma unroll
    for (int i = 0; i < NN; ++i) dh[i] = -2.0f * x0[i];

    float Lfhx = 0.0f;
#pragma unroll
    for (int i = 0; i < NN; ++i) {
        const float4 aq0 = *(const float4*)(Amat + i * NN);
        const float4 aq1 = *(const float4*)(Amat + i * NN + 4);
        float fx = 0.0f;
        fx = fmaf(aq0.x, x0[0], fx); fx = fmaf(aq0.y, x0[1], fx);
        fx = fmaf(aq0.z, x0[2], fx); fx = fmaf(aq0.w, x0[3], fx);
        fx = fmaf(aq1.x, x0[4], fx); fx = fmaf(aq1.y, x0[5], fx);
        fx = fmaf(aq1.z, x0[6], fx); fx = fmaf(aq1.w, x0[7], fx);
        Lfhx = fmaf(dh[i], fx, Lfhx);
    }

#define GDECL(j) float g##j = 0.0f;
    FOR8(GDECL)
#undef GDECL
#pragma unroll
    for (int i = 0; i < NN; ++i) {
        const float4 gq0 = *(const float4*)(Gmat + i * MM);
        const float4 gq1 = *(const float4*)(Gmat + i * MM + 4);
        const float da = dh[i];
        g0 = fmaf(da, gq0.x, g0); g1 = fmaf(da, gq0.y, g1);
        g2 = fmaf(da, gq0.z, g2); g3 = fmaf(da, gq0.w, g3);
        g4 = fmaf(da, gq1.x, g4); g5 = fmaf(da, gq1.y, g5);
        g6 = fmaf(da, gq1.z, g6); g7 = fmaf(da, gq1.w, g7);
    }

    const float c0 = fmaf(alphax, hx, Lfhx);

    // =====================================================================
    // QP via exact piecewise-linear root isolation — fully scalarized.
    // =====================================================================
#define DECL_PG(j) const float p##j = (j & 1) ? pv[j >> 1].y : pv[j >> 1].x;
    FOR8(DECL_PG)
#undef DECL_PG

    auto c_of = [&](float lam) -> float {
        float c = c0;
#define CTERM(j) { float u = fmaf(lam, g##j, -p##j);                  \
                   u = fminf(fmaxf(u, -1.0f), 1.0f);                  \
                   c = fmaf(g##j, u, c); }
        FOR8(CTERM)
#undef CTERM
        return c;
    };

    const bool viol = (c_of(0.0f) < 0.0f);

    const float BIGR = 3.0e38f;         // sentinel: no right bracket found
    float lamL = 0.0f, lamR = BIGR;
#define BP(j) {                                                        \
        const float rg = __builtin_amdgcn_rcpf(g##j);                  \
        const float bpa = (p##j - 1.0f) * rg;                          \
        const float bpb = (p##j + 1.0f) * rg;                          \
        const float ca = c_of(bpa);                                    \
        const float cb = c_of(bpb);                                    \
        lamL = (bpa > 0.0f && ca <  0.0f && bpa > lamL) ? bpa : lamL;  \
        lamR = (bpa > 0.0f && ca >= 0.0f && bpa < lamR) ? bpa : lamR;  \
        lamL = (bpb > 0.0f && cb <  0.0f && bpb > lamL) ? bpb : lamL;  \
        lamR = (bpb > 0.0f && cb >= 0.0f && bpb < lamR) ? bpb : lamR;  \
    }
    FOR8(BP)
#undef BP

    const bool infeas = (lamR == BIGR);
    float lam_t = infeas ? 1.099511627776e12f : 0.5f * (lamL + lamR);
    lam_t = viol ? lam_t : 0.0f;

    float denom = 0.0f, num = c0;
#define ASET(j)                                                        \
    const float ur##j = fmaf(lam_t, g##j, -p##j);                      \
    const bool lo##j = (ur##j <= -1.0f);                               \
    const bool hi##j = (ur##j >=  1.0f);                               \
    denom += (!(lo##j || hi##j)) ? g##j * g##j : 0.0f;                 \
    num   += lo##j ? -g##j : (hi##j ? g##j : -g##j * p##j);
    FOR8(ASET)
#undef ASET

    const float lam = viol ? (-num / (denom + 1e-12f)) : 0.0f;

#define UOUT(j) const float uo##j =                                    \
    lo##j ? -1.0f : (hi##j ? 1.0f : fmaf(lam, g##j, -p##j));
    FOR8(UOUT)
#undef UOUT

    float4* ov = reinterpret_cast<float4*>(out + (size_t)row * MM);
    ov[0] = make_float4(uo0, uo1, uo2, uo3);
    ov[1] = make_float4(uo4, uo5, uo6, uo7);
}

#define ARGS_DECL                                                       \
    const float* __restrict__ x_g,                                      \
    const float* __restrict__ W1,  const float* __restrict__ b1,        \
    const float* __restrict__ W21, const float* __restrict__ b21,       \
    const float* __restrict__ W22, const float* __restrict__ b22,       \
    const float* __restrict__ W31, const float* __restrict__ b31,       \
    const float* __restrict__ W32, const float* __restrict__ b32,       \
    const float* __restrict__ Amat, const float* __restrict__ Gmat,     \
    const float* __restrict__ mean, const float* __restrict__ std_,    \
    float* __restrict__ out
#define ARGS_PASS x_g, W1, b1, W21, b21, W22, b22, W31, b31, W32, b32, \
                  Amat, Gmat, mean, std_, out

__global__ __launch_bounds__(256, 2) void barrier_policy_clean(ARGS_DECL)
{
    const int row = blockIdx.x * 256 + threadIdx.x;
    compute_row(row, ARGS_PASS);
}

__global__ __launch_bounds__(256, 2) void barrier_policy_guard(ARGS_DECL, int B)
{
    const int row = blockIdx.x * 256 + threadIdx.x;
    if (row < B) compute_row(row, ARGS_PASS);
}

extern "C" void kernel_launch(void* const* d_in, const int* in_sizes, int n_in,
                              void* d_out, int out_size, void* d_ws, size_t ws_size,
                              hipStream_t stream) {
    const float* x    = (const float*)d_in[0];
    const float* W1   = (const float*)d_in[1];
    const float* b1   = (const float*)d_in[2];
    const float* W21  = (const float*)d_in[3];
    const float* b21  = (const float*)d_in[4];
    const float* W22  = (const float*)d_in[5];
    const float* b22  = (const float*)d_in[6];
    const float* W31  = (const float*)d_in[7];
    const float* b31  = (const float*)d_in[8];
    const float* W32  = (const float*)d_in[9];
    const float* b32  = (const float*)d_in[10];
    const float* Amat = (const float*)d_in[11];
    const float* Gmat = (const float*)d_in[12];
    const float* mean = (const float*)d_in[13];
    const float* std_ = (const float*)d_in[14];
    float* out = (float*)d_out;

    const int B = in_sizes[0] / NN;
    if (B % 256 == 0) {
        barrier_policy_clean<<<B / 256, 256, 0, stream>>>(
            x, W1, b1, W21, b21, W22, b22, W31, b31, W32, b32,
            Amat, Gmat, mean, std_, out);
    } else {
        barrier_policy_guard<<<(B + 255) / 256, 256, 0, stream>>>(
            x, W1, b1, W21, b21, W22, b22, W31, b31, W32, b32,
            Amat, Gmat, mean, std_, out, B);
    }
}